// Round 5
// baseline (692.896 us; speedup 1.0000x reference)
//
#include <hip/hip_runtime.h>

#define T_LEN 32768
#define B_N   64
#define SEG   64
#define WARM  64
#define NSEG  (T_LEN / SEG)        // 512 segments/sample
#define WPS   (NSEG / 32)          // 16 waves/sample (32 streams per wave)
#define CSKIP (WARM / 32)          // 2 warm chunks
#define NCH   (CSKIP + SEG / 32)   // 4 chunks of 32 steps
#define XROW  33                   // x LDS row stride (banks (m+tt)%32, conflict-free)
#define YROW  33                   // y LDS row stride

typedef __fp16 half2v __attribute__((ext_vector_type(2)));
typedef __fp16 half8  __attribute__((ext_vector_type(8)));
typedef float  f32x16 __attribute__((ext_vector_type(16)));

#define MFMA(a, b, c) __builtin_amdgcn_mfma_f32_32x32x16_f16((a), (b), (c), 0, 0, 0)

#if __has_builtin(__builtin_amdgcn_fdot2)
#define FDOT2(a, b, c) __builtin_amdgcn_fdot2((a), (b), (c), false)
#else
static __device__ __forceinline__ float fdot2_emul(half2v a, half2v b, float c) {
    return fmaf((float)a.x, (float)b.x, fmaf((float)a.y, (float)b.y, c));
}
#define FDOT2(a, b, c) fdot2_emul((a), (b), (c))
#endif

union BU { half2v h2[4]; half8 h8; };

// Row permutation rho (involution): swaps 4..7 <-> 8..11. Chosen so the
// 32x32 MFMA D-layout (row = (reg&3)+8*(reg>>2)+4*kh, col = lane&31) lands
// each lane's gate outputs on jj = 8*kh + reg — exactly the B-fragment
// k-split (lane kh-half holds k = 8*kh + 0..7). So D -> B repack per step
// is 4 cvt_pkrtz with ZERO cross-lane ops. (HW-verified: r4 passed.)
__device__ __forceinline__ int rho(int v) {
    const int q = v >> 2;
    return (q == 1) ? v + 4 : (q == 2) ? v - 4 : v;
}

// r24: SPILL KILL. r4's MFMA rewrite was correct but allocated 256 VGPR and
// spilled ~65 MB/launch to scratch (WRITE 74 MB vs 8.4 MB output) — a
// scratch round-trip on the recurrence chain every step (2043 cy/step vs
// ~300 cy of issue). This round only reduces register pressure:
//  - warm/main chunk loops split (h0v8 + pin logic dead after warmup)
//  - no register x-prefetch: direct global->LDS staging between barriers
//    (exposed ~600 cy x 4 chunks ~ 1 us total, vs spill's ~1700 cy/step)
//  - slot-31 y via 4 packed fdot2 on Bu (drops f32 owv8[8])
//  - sched_barrier(0) every 2 steps bounds cross-step hoisting; xt ds_reads
//    prefetched one pair ahead in 2 regs so LDS latency hides across the
//    scheduling boundary
//  - ylds writes skipped in warm chunks
// Math identical to r4 (passed, absmax 2^-8).
__global__ __launch_bounds__(64, 1) void hyper_gru_kernel(
    const float* __restrict__ x,     const float* __restrict__ c,    const float* __restrict__ h0,
    const float* __restrict__ w1,    const float* __restrict__ b1,
    const float* __restrict__ w2,    const float* __restrict__ b2,
    const float* __restrict__ pihw,  const float* __restrict__ pihb,
    const float* __restrict__ phhw,  const float* __restrict__ phhb,
    const float* __restrict__ pbihw, const float* __restrict__ pbihb,
    const float* __restrict__ pbhhw, const float* __restrict__ pbhhb,
    const float* __restrict__ oww,   const float* __restrict__ owb,
    float* __restrict__ out)
{
    const int blk = blockIdx.x;
    const int b   = blk / WPS;         // sample
    const int w   = blk - b * WPS;     // wave index within sample (16 waves)
    const int ln  = threadIdx.x;
    const int m   = ln & 31;           // A-row / D-col / B-col (stream id)
    const int kh  = ln >> 5;           // k-half (0: k=0..7, 1: k=8..15)

    __shared__ float xlds[32 * XROW];
    __shared__ float ylds[32 * YROW];
    __shared__ float sp[2][48];        // A-row partial sums for bias folds

    // ---- hypernetwork: cond MLP -> a2[8] (uniform; redundant per lane) ----
    float cv[8], a1m[8], a2m[8];
    #pragma unroll
    for (int n = 0; n < 8; ++n) cv[n] = c[b*8 + n];
    #pragma unroll
    for (int mm = 0; mm < 8; ++mm) {
        float sv = b1[mm];
        #pragma unroll
        for (int n = 0; n < 8; ++n) sv = fmaf(cv[n], w1[mm*8 + n], sv);
        a1m[mm] = (sv >= 0.f) ? sv : 0.1f * sv;
    }
    #pragma unroll
    for (int mm = 0; mm < 8; ++mm) {
        float sv = b2[mm];
        #pragma unroll
        for (int k = 0; k < 8; ++k) sv = fmaf(a1m[k], w2[mm*8 + k], sv);
        a2m[mm] = (sv >= 0.f) ? sv : 0.1f * sv;
    }
    auto proj = [&](const float* W, const float* Bv, int row) {
        float sv = Bv[row];
        #pragma unroll
        for (int mm = 0; mm < 8; ++mm) sv = fmaf(a2m[mm], W[row*8 + mm], sv);
        return sv;
    };

    // Scales folded in: r,i: -log2e (sigmoid = rcp(1+exp2(acc)));
    //                   n:   -2log2e (tanh = 2*rcp(1+exp2(acc)) - 1)
    const float SC1 = -1.44269504f, SC2 = -2.88539008f;

    // ---- A fragments (lane owns row m, k = 8*kh + 0..7) ----
    BU A1u, A2u;
    {
        float a1v[8]; float part1 = 0.f;
        const int jw1 = (m < 16) ? rho(m) : 16 + rho(m - 16);   // phh column
        #pragma unroll
        for (int i = 0; i < 8; ++i) {
            const int k = 8*kh + i;
            a1v[i] = SC1 * proj(phhw, phhb, k*48 + jw1);
            part1 += a1v[i];
        }
        __builtin_amdgcn_sched_barrier(0);
        float a2v[8]; float part2 = 0.f;
        if (m < 16) {
            const int jw2 = 32 + rho(m);
            #pragma unroll
            for (int i = 0; i < 8; ++i) {
                const int k = 8*kh + i;
                a2v[i] = SC2 * proj(phhw, phhb, k*48 + jw2);
                part2 += a2v[i];
            }
        } else if (m == 16) {
            #pragma unroll
            for (int i = 0; i < 8; ++i) a2v[i] = oww[8*kh + i];
        } else {
            #pragma unroll
            for (int i = 0; i < 8; ++i) a2v[i] = 0.f;
        }
        __builtin_amdgcn_sched_barrier(0);
        #pragma unroll
        for (int r = 0; r < 4; ++r) {
            A1u.h2[r] = __builtin_amdgcn_cvt_pkrtz(a1v[2*r], a1v[2*r+1]);
            A2u.h2[r] = __builtin_amdgcn_cvt_pkrtz(a2v[2*r], a2v[2*r+1]);
        }
        sp[kh][m] = part1;
        if (m < 16) sp[kh][32 + m] = part2;
    }
    __syncthreads();

    // ---- per-lane constants for jj = 8*kh + i ----
    float wihR[8], wihI[8], wihN[8], biasR[8], biasI[8], bihN[8];
    f32x16 c2;                                  // [biasAN x8, obv, 0...]
    #pragma unroll
    for (int i = 0; i < 8; ++i) {
        const int jj = 8*kh + i;
        const int rr = rho(jj);
        const float sWr = sp[0][rr]      + sp[1][rr];
        const float sWi = sp[0][16 + rr] + sp[1][16 + rr];
        const float sWn = sp[0][32 + rr] + sp[1][32 + rr];
        wihR[i]   = SC1 * proj(pihw, pihb, jj);
        wihI[i]   = SC1 * proj(pihw, pihb, 16 + jj);
        wihN[i]   = SC2 * proj(pihw, pihb, 32 + jj);
        biasR[i]  = SC1 * (proj(pbihw, pbihb, jj) + proj(pbhhw, pbhhb, jj)) - sWr;
        biasI[i]  = SC1 * (proj(pbihw, pbihb, 16 + jj) + proj(pbhhw, pbhhb, 16 + jj)) - sWi;
        bihN[i]   = SC2 * proj(pbihw, pbihb, 32 + jj);
        c2[i]     = SC2 * proj(pbhhw, pbhhb, 32 + jj) - sWn;   // biasAN
        __builtin_amdgcn_sched_barrier(0);
    }
    // packed output weights (for slot-31 direct y) and obv
    half2v owp[4];
    {
        float sumow = 0.f;
        #pragma unroll
        for (int k = 0; k < 16; ++k) sumow += oww[k];
        #pragma unroll
        for (int r = 0; r < 4; ++r)
            owp[r] = __builtin_amdgcn_cvt_pkrtz(oww[8*kh + 2*r], oww[8*kh + 2*r + 1]);
        c2[8] = owb[0] - sumow;                 // obv
        #pragma unroll
        for (int i = 9; i < 16; ++i) c2[i] = 0.f;
    }
    const float obv = c2[8];
    __builtin_amdgcn_sched_barrier(0);

    // ---- state init: H = h+1; col 0 of wave 0 pinned to true h0 ----
    const bool pinlane = (w == 0) && (m == 0);
    float Hd[8];
    BU Bu;
    float h0v8[8];
    #pragma unroll
    for (int i = 0; i < 8; ++i) h0v8[i] = h0[b*16 + 8*kh + i] + 1.f;
    #pragma unroll
    for (int i = 0; i < 8; ++i) Hd[i] = pinlane ? h0v8[i] : 1.f;
    #pragma unroll
    for (int r = 0; r < 4; ++r) Bu.h2[r] = __builtin_amdgcn_cvt_pkrtz(Hd[2*r], Hd[2*r+1]);

    // ---- x staging: direct global -> LDS (16 transient regs, no persistence) ----
    const int xoff = b*T_LEN + (32*w + m)*SEG - WARM + 16*kh;  // 16-float aligned when >= 0
    auto stage = [&](int cc) {
        const int xb = xoff + cc*32;
        float v[16];
        if (xb >= 0) {
            const float4* xp = (const float4*)(x + xb);
            #pragma unroll
            for (int j = 0; j < 4; ++j) {
                const float4 t = xp[j];
                v[4*j+0] = t.x; v[4*j+1] = t.y; v[4*j+2] = t.z; v[4*j+3] = t.w;
            }
        } else {
            #pragma unroll
            for (int i = 0; i < 16; ++i) {
                int idx = xb + i;
                idx = (idx < 0) ? 0 : idx;
                v[i] = x[idx];
            }
        }
        #pragma unroll
        for (int i = 0; i < 16; ++i) xlds[m*XROW + 16*kh + i] = v[i];
    };
    stage(0);
    __syncthreads();

    // ---- one GRU step for all 32 streams (xt passed in registers) ----
    auto stepf = [&](int tt, float xt, bool warmf) {
        f32x16 c1;
        #pragma unroll
        for (int i = 0; i < 8; ++i) c1[i]     = fmaf(xt, wihR[i], biasR[i]);
        #pragma unroll
        for (int i = 0; i < 8; ++i) c1[8 + i] = fmaf(xt, wihI[i], biasI[i]);
        const f32x16 d1 = MFMA(A1u.h8, Bu.h8, c1);
        const f32x16 d2 = MFMA(A2u.h8, Bu.h8, c2);
        float ipN[8];
        #pragma unroll
        for (int i = 0; i < 8; ++i) ipN[i] = fmaf(xt, wihN[i], bihN[i]);
        float hn[8];
        #pragma unroll
        for (int i = 0; i < 8; ++i) {
            const float ur  = __builtin_amdgcn_rcpf(1.f + __builtin_amdgcn_exp2f(d1[i]));
            const float ui  = __builtin_amdgcn_rcpf(1.f + __builtin_amdgcn_exp2f(d1[8 + i]));
            const float tno = fmaf(ur, d2[i], ipN[i]);
            const float un  = __builtin_amdgcn_rcpf(1.f + __builtin_amdgcn_exp2f(tno));
            hn[i] = fmaf(ui, fmaf(-2.f, un, Hd[i]), un + un);   // H' = 2u + i*(H-2u)
        }
        if (warmf) {
            #pragma unroll
            for (int i = 0; i < 8; ++i) hn[i] = pinlane ? h0v8[i] : hn[i];
        }
        #pragma unroll
        for (int i = 0; i < 8; ++i) Hd[i] = hn[i];
        #pragma unroll
        for (int r = 0; r < 4; ++r) Bu.h2[r] = __builtin_amdgcn_cvt_pkrtz(hn[2*r], hn[2*r+1]);
        if (!warmf && kh == 0)
            ylds[m*YROW + ((tt + 31) & 31)] = d2[8];   // y_{t-1} from mfma row 16
    };

    // 32 steps of one chunk; xt prefetched one pair ahead (2 regs);
    // sched_barrier(0) per pair bounds cross-step hoisting (anti-spill).
    auto runchunk = [&](bool warmf) {
        const float* xr = xlds + m*XROW;
        float x0 = xr[0], x1 = xr[1];
        #pragma unroll
        for (int tt = 0; tt < 32; tt += 2) {
            const int i2 = (tt + 2 < 32) ? tt + 2 : 31;
            const int i3 = (tt + 3 < 32) ? tt + 3 : 31;
            const float x2 = xr[i2], x3 = xr[i3];
            stepf(tt,     x0, warmf);
            stepf(tt + 1, x1, warmf);
            x0 = x2; x1 = x3;
            __builtin_amdgcn_sched_barrier(0);
        }
    };

    // ---- warm chunks (pin logic + h0v8 die here) ----
    for (int cc = 0; cc < CSKIP; ++cc) {
        runchunk(true);
        __syncthreads();           // xlds reads done
        stage(cc + 1);
        __syncthreads();           // xlds ready
    }

    // ---- main chunks ----
    for (int cc = CSKIP; cc < NCH; ++cc) {
        runchunk(false);
        {   // slot-31 y from the current (post-chunk) H via packed fdot2 on Bu
            float p = FDOT2(Bu.h2[0], owp[0], 0.f);
            p = FDOT2(Bu.h2[1], owp[1], p);
            p = FDOT2(Bu.h2[2], owp[2], p);
            p = FDOT2(Bu.h2[3], owp[3], p);
            const float p2 = __shfl_xor(p, 32, 64);
            if (kh == 0) ylds[m*YROW + 31] = obv + p + p2;
        }
        __syncthreads();           // ylds complete; xlds reads done

        {   // write 32 streams x 32 steps; lane: col m, slots 16*kh..+15
            const int tbase = b*T_LEN + (32*w + m)*SEG + (cc - CSKIP)*32 + 16*kh;
            #pragma unroll
            for (int j = 0; j < 4; ++j) {
                float4 o;
                o.x = ylds[m*YROW + 16*kh + 4*j + 0];
                o.y = ylds[m*YROW + 16*kh + 4*j + 1];
                o.z = ylds[m*YROW + 16*kh + 4*j + 2];
                o.w = ylds[m*YROW + 16*kh + 4*j + 3];
                *(float4*)(out + tbase + 4*j) = o;
            }
        }
        if (cc + 1 < NCH) stage(cc + 1);
        __syncthreads();           // xlds ready for next chunk
    }

    // h_last [B,1,R]: last stream = col 31 of wave WPS-1 (exact f32 state)
    if (w == WPS - 1 && m == 31) {
        #pragma unroll
        for (int i = 0; i < 8; ++i)
            out[B_N * T_LEN + b*16 + 8*kh + i] = Hd[i] - 1.f;
    }
}

extern "C" void kernel_launch(void* const* d_in, const int* in_sizes, int n_in,
                              void* d_out, int out_size, void* d_ws, size_t ws_size,
                              hipStream_t stream) {
    (void)in_sizes; (void)n_in; (void)d_ws; (void)ws_size; (void)out_size;
    hipLaunchKernelGGL(hyper_gru_kernel, dim3(B_N * WPS), dim3(64), 0, stream,
        (const float*)d_in[0],  (const float*)d_in[1],  (const float*)d_in[2],
        (const float*)d_in[3],  (const float*)d_in[4],  (const float*)d_in[5],  (const float*)d_in[6],
        (const float*)d_in[7],  (const float*)d_in[8],  (const float*)d_in[9],  (const float*)d_in[10],
        (const float*)d_in[11], (const float*)d_in[12], (const float*)d_in[13], (const float*)d_in[14],
        (const float*)d_in[15], (const float*)d_in[16],
        (float*)d_out);
}

// Round 6
// 178.515 us; speedup vs baseline: 3.8814x; 3.8814x over previous
//
#include <hip/hip_runtime.h>

#define T_LEN 32768
#define B_N   64
#define SEG   64
#define WARM  64
#define NSEG  (T_LEN / SEG)        // 512 segments/sample
#define WPS   (NSEG / 32)          // 16 waves/sample (32 streams per wave)
#define CSKIP (WARM / 32)          // 2 warm chunks
#define NCH   (CSKIP + SEG / 32)   // 4 chunks of 32 steps
#define XROW  33                   // x LDS row stride (banks (m+tt)%32, conflict-free)
#define YROW  33                   // y LDS row stride

typedef __fp16 half2v __attribute__((ext_vector_type(2)));
typedef __fp16 half8  __attribute__((ext_vector_type(8)));
typedef float  f32x16 __attribute__((ext_vector_type(16)));

#define MFMA(a, b, c) __builtin_amdgcn_mfma_f32_32x32x16_f16((a), (b), (c), 0, 0, 0)

#if __has_builtin(__builtin_amdgcn_fdot2)
#define FDOT2(a, b, c) __builtin_amdgcn_fdot2((a), (b), (c), false)
#else
static __device__ __forceinline__ float fdot2_emul(half2v a, half2v b, float c) {
    return fmaf((float)a.x, (float)b.x, fmaf((float)a.y, (float)b.y, c));
}
#define FDOT2(a, b, c) fdot2_emul((a), (b), (c))
#endif

union BU { half2v h2[4]; half8 h8; };

// Row permutation rho (involution): swaps 4..7 <-> 8..11. Chosen so the
// 32x32 MFMA D-layout (row = (reg&3)+8*(reg>>2)+4*kh, col = lane&31) lands
// each lane's gate outputs on jj = 8*kh + reg — exactly the B-fragment
// k-split (lane kh-half holds k = 8*kh + 0..7). So D -> B repack per step
// is 4 cvt_pkrtz with ZERO cross-lane ops. (HW-verified: r4 passed.)
__device__ __forceinline__ int rho(int v) {
    const int q = v >> 2;
    return (q == 1) ? v + 4 : (q == 2) ? v - 4 : v;
}

// r25: INLINE GUARANTEE. r5's regression (109 -> 630 us, WRITE 74 -> 349 MB
// at VGPR=140) was the runchunk lambda (32 inlined steps, 2 call sites)
// getting OUTLINED by the inliner — all [&] captures materialized to
// scratch, every step became scratch round-trips (L2-served: VALUBusy 8%).
// Fix: the step body and x-staging are MACROS (textual inlining, nothing to
// outline) and the warm/main split collapses into ONE chunk loop with a
// runtime warm flag (pin = 8 cndmask/step, trivial), so the unrolled step
// body exists exactly once. Keeps r5's pressure cuts: no persistent
// register x-prefetch, packed-fdot2 slot-31 y, per-pair sched_barrier(0)
// + 2-reg xt prefetch. Math identical to r4/r5 (passed, absmax 2^-8).

// ---- one GRU step for all 32 streams (macro: textual inlining) ----
#define GRU_STEP(TT, XT) do {                                                  \
    f32x16 c1;                                                                 \
    _Pragma("unroll")                                                          \
    for (int i = 0; i < 8; ++i) c1[i]     = fmaf((XT), wihR[i], biasR[i]);     \
    _Pragma("unroll")                                                          \
    for (int i = 0; i < 8; ++i) c1[8 + i] = fmaf((XT), wihI[i], biasI[i]);     \
    const f32x16 d1 = MFMA(A1u.h8, Bu.h8, c1);                                 \
    const f32x16 d2 = MFMA(A2u.h8, Bu.h8, c2);                                 \
    float ipN[8], hn[8];                                                       \
    _Pragma("unroll")                                                          \
    for (int i = 0; i < 8; ++i) ipN[i] = fmaf((XT), wihN[i], bihN[i]);         \
    _Pragma("unroll")                                                          \
    for (int i = 0; i < 8; ++i) {                                              \
        const float ur  = __builtin_amdgcn_rcpf(1.f + __builtin_amdgcn_exp2f(d1[i]));     \
        const float ui  = __builtin_amdgcn_rcpf(1.f + __builtin_amdgcn_exp2f(d1[8 + i])); \
        const float tno = fmaf(ur, d2[i], ipN[i]);                             \
        const float un  = __builtin_amdgcn_rcpf(1.f + __builtin_amdgcn_exp2f(tno));       \
        hn[i] = fmaf(ui, fmaf(-2.f, un, Hd[i]), un + un);                      \
    }                                                                          \
    _Pragma("unroll")                                                          \
    for (int i = 0; i < 8; ++i) hn[i] = dopin ? h0v8[i] : hn[i];               \
    _Pragma("unroll")                                                          \
    for (int i = 0; i < 8; ++i) Hd[i] = hn[i];                                 \
    _Pragma("unroll")                                                          \
    for (int r = 0; r < 4; ++r)                                                \
        Bu.h2[r] = __builtin_amdgcn_cvt_pkrtz(hn[2*r], hn[2*r+1]);             \
    if (doy) ylds[m*YROW + (((TT) + 31) & 31)] = d2[8];                        \
} while (0)

// ---- x staging: direct global -> LDS, transient regs only (macro) ----
#define STAGE_X(CC) do {                                                       \
    const int xb_ = xoff + (CC)*32;                                            \
    float v_[16];                                                              \
    if (xb_ >= 0) {                                                            \
        const float4* xp_ = (const float4*)(x + xb_);                          \
        _Pragma("unroll")                                                      \
        for (int j = 0; j < 4; ++j) {                                          \
            const float4 t_ = xp_[j];                                          \
            v_[4*j+0] = t_.x; v_[4*j+1] = t_.y;                                \
            v_[4*j+2] = t_.z; v_[4*j+3] = t_.w;                                \
        }                                                                      \
    } else {                                                                   \
        _Pragma("unroll")                                                      \
        for (int i = 0; i < 16; ++i) {                                         \
            int idx_ = xb_ + i;                                                \
            idx_ = (idx_ < 0) ? 0 : idx_;                                      \
            v_[i] = x[idx_];                                                   \
        }                                                                      \
    }                                                                          \
    _Pragma("unroll")                                                          \
    for (int i = 0; i < 16; ++i) xlds[m*XROW + 16*kh + i] = v_[i];             \
} while (0)

__global__ __launch_bounds__(64, 1) void hyper_gru_kernel(
    const float* __restrict__ x,     const float* __restrict__ c,    const float* __restrict__ h0,
    const float* __restrict__ w1,    const float* __restrict__ b1,
    const float* __restrict__ w2,    const float* __restrict__ b2,
    const float* __restrict__ pihw,  const float* __restrict__ pihb,
    const float* __restrict__ phhw,  const float* __restrict__ phhb,
    const float* __restrict__ pbihw, const float* __restrict__ pbihb,
    const float* __restrict__ pbhhw, const float* __restrict__ pbhhb,
    const float* __restrict__ oww,   const float* __restrict__ owb,
    float* __restrict__ out)
{
    const int blk = blockIdx.x;
    const int b   = blk / WPS;         // sample
    const int w   = blk - b * WPS;     // wave index within sample (16 waves)
    const int ln  = threadIdx.x;
    const int m   = ln & 31;           // A-row / D-col / B-col (stream id)
    const int kh  = ln >> 5;           // k-half (0: k=0..7, 1: k=8..15)

    __shared__ float xlds[32 * XROW];
    __shared__ float ylds[32 * YROW];
    __shared__ float sp[2][48];        // A-row partial sums for bias folds

    // ---- hypernetwork: cond MLP -> a2[8] (uniform; redundant per lane) ----
    float cv[8], a1m[8], a2m[8];
    #pragma unroll
    for (int n = 0; n < 8; ++n) cv[n] = c[b*8 + n];
    #pragma unroll
    for (int mm = 0; mm < 8; ++mm) {
        float sv = b1[mm];
        #pragma unroll
        for (int n = 0; n < 8; ++n) sv = fmaf(cv[n], w1[mm*8 + n], sv);
        a1m[mm] = (sv >= 0.f) ? sv : 0.1f * sv;
    }
    #pragma unroll
    for (int mm = 0; mm < 8; ++mm) {
        float sv = b2[mm];
        #pragma unroll
        for (int k = 0; k < 8; ++k) sv = fmaf(a1m[k], w2[mm*8 + k], sv);
        a2m[mm] = (sv >= 0.f) ? sv : 0.1f * sv;
    }
    auto proj = [&](const float* W, const float* Bv, int row) {
        float sv = Bv[row];
        #pragma unroll
        for (int mm = 0; mm < 8; ++mm) sv = fmaf(a2m[mm], W[row*8 + mm], sv);
        return sv;
    };

    // Scales folded in: r,i: -log2e (sigmoid = rcp(1+exp2(acc)));
    //                   n:   -2log2e (tanh = 2*rcp(1+exp2(acc)) - 1)
    const float SC1 = -1.44269504f, SC2 = -2.88539008f;

    // ---- A fragments (lane owns row m, k = 8*kh + 0..7) ----
    BU A1u, A2u;
    {
        float a1v[8]; float part1 = 0.f;
        const int jw1 = (m < 16) ? rho(m) : 16 + rho(m - 16);   // phh column
        #pragma unroll
        for (int i = 0; i < 8; ++i) {
            const int k = 8*kh + i;
            a1v[i] = SC1 * proj(phhw, phhb, k*48 + jw1);
            part1 += a1v[i];
        }
        __builtin_amdgcn_sched_barrier(0);
        float a2v[8]; float part2 = 0.f;
        if (m < 16) {
            const int jw2 = 32 + rho(m);
            #pragma unroll
            for (int i = 0; i < 8; ++i) {
                const int k = 8*kh + i;
                a2v[i] = SC2 * proj(phhw, phhb, k*48 + jw2);
                part2 += a2v[i];
            }
        } else if (m == 16) {
            #pragma unroll
            for (int i = 0; i < 8; ++i) a2v[i] = oww[8*kh + i];
        } else {
            #pragma unroll
            for (int i = 0; i < 8; ++i) a2v[i] = 0.f;
        }
        __builtin_amdgcn_sched_barrier(0);
        #pragma unroll
        for (int r = 0; r < 4; ++r) {
            A1u.h2[r] = __builtin_amdgcn_cvt_pkrtz(a1v[2*r], a1v[2*r+1]);
            A2u.h2[r] = __builtin_amdgcn_cvt_pkrtz(a2v[2*r], a2v[2*r+1]);
        }
        sp[kh][m] = part1;
        if (m < 16) sp[kh][32 + m] = part2;
    }
    __syncthreads();

    // ---- per-lane constants for jj = 8*kh + i ----
    float wihR[8], wihI[8], wihN[8], biasR[8], biasI[8], bihN[8];
    f32x16 c2;                                  // [biasAN x8, obv, 0...]
    #pragma unroll
    for (int i = 0; i < 8; ++i) {
        const int jj = 8*kh + i;
        const int rr = rho(jj);
        const float sWr = sp[0][rr]      + sp[1][rr];
        const float sWi = sp[0][16 + rr] + sp[1][16 + rr];
        const float sWn = sp[0][32 + rr] + sp[1][32 + rr];
        wihR[i]   = SC1 * proj(pihw, pihb, jj);
        wihI[i]   = SC1 * proj(pihw, pihb, 16 + jj);
        wihN[i]   = SC2 * proj(pihw, pihb, 32 + jj);
        biasR[i]  = SC1 * (proj(pbihw, pbihb, jj) + proj(pbhhw, pbhhb, jj)) - sWr;
        biasI[i]  = SC1 * (proj(pbihw, pbihb, 16 + jj) + proj(pbhhw, pbhhb, 16 + jj)) - sWi;
        bihN[i]   = SC2 * proj(pbihw, pbihb, 32 + jj);
        c2[i]     = SC2 * proj(pbhhw, pbhhb, 32 + jj) - sWn;   // biasAN
        __builtin_amdgcn_sched_barrier(0);
    }
    // packed output weights (for slot-31 direct y) and obv
    half2v owp[4];
    {
        float sumow = 0.f;
        #pragma unroll
        for (int k = 0; k < 16; ++k) sumow += oww[k];
        #pragma unroll
        for (int r = 0; r < 4; ++r)
            owp[r] = __builtin_amdgcn_cvt_pkrtz(oww[8*kh + 2*r], oww[8*kh + 2*r + 1]);
        c2[8] = owb[0] - sumow;                 // obv
        #pragma unroll
        for (int i = 9; i < 16; ++i) c2[i] = 0.f;
    }
    const float obv = c2[8];
    __builtin_amdgcn_sched_barrier(0);

    // ---- state init: H = h+1; col 0 of wave 0 pinned to true h0 ----
    const bool pinlane = (w == 0) && (m == 0);
    float Hd[8], h0v8[8];
    BU Bu;
    #pragma unroll
    for (int i = 0; i < 8; ++i) h0v8[i] = h0[b*16 + 8*kh + i] + 1.f;
    #pragma unroll
    for (int i = 0; i < 8; ++i) Hd[i] = pinlane ? h0v8[i] : 1.f;
    #pragma unroll
    for (int r = 0; r < 4; ++r) Bu.h2[r] = __builtin_amdgcn_cvt_pkrtz(Hd[2*r], Hd[2*r+1]);

    const int xoff = b*T_LEN + (32*w + m)*SEG - WARM + 16*kh;  // 16-float aligned when >= 0
    STAGE_X(0);
    __syncthreads();

    // ---- single chunk loop; warm handling via runtime flags ----
    for (int cc = 0; cc < NCH; ++cc) {
        const bool warmf = (cc < CSKIP);
        const bool dopin = warmf && pinlane;       // 8 cndmask/step, trivial
        const bool doy   = !warmf && (kh == 0);
        const float* xr = xlds + m*XROW;
        float x0 = xr[0], x1 = xr[1];
        #pragma unroll
        for (int tt = 0; tt < 32; tt += 2) {
            const int i2 = (tt + 2 < 32) ? tt + 2 : 31;
            const int i3 = (tt + 3 < 32) ? tt + 3 : 31;
            const float x2 = xr[i2], x3 = xr[i3];
            GRU_STEP(tt,     x0);
            GRU_STEP(tt + 1, x1);
            x0 = x2; x1 = x3;
            __builtin_amdgcn_sched_barrier(0);     // bound cross-step hoisting
        }

        if (!warmf) {
            // slot-31 y from the current (post-chunk) H via packed fdot2 on Bu
            float p = FDOT2(Bu.h2[0], owp[0], 0.f);
            p = FDOT2(Bu.h2[1], owp[1], p);
            p = FDOT2(Bu.h2[2], owp[2], p);
            p = FDOT2(Bu.h2[3], owp[3], p);
            const float p2 = __shfl_xor(p, 32, 64);
            if (kh == 0) ylds[m*YROW + 31] = obv + p + p2;
        }
        __syncthreads();           // ylds complete; xlds reads done

        if (!warmf) {
            // write 32 streams x 32 steps; lane: col m, slots 16*kh..+15
            const int tbase = b*T_LEN + (32*w + m)*SEG + (cc - CSKIP)*32 + 16*kh;
            #pragma unroll
            for (int j = 0; j < 4; ++j) {
                float4 o;
                o.x = ylds[m*YROW + 16*kh + 4*j + 0];
                o.y = ylds[m*YROW + 16*kh + 4*j + 1];
                o.z = ylds[m*YROW + 16*kh + 4*j + 2];
                o.w = ylds[m*YROW + 16*kh + 4*j + 3];
                *(float4*)(out + tbase + 4*j) = o;
            }
        }
        if (cc + 1 < NCH) STAGE_X(cc + 1);
        __syncthreads();           // xlds ready for next chunk
    }

    // h_last [B,1,R]: last stream = col 31 of wave WPS-1 (exact f32 state)
    if (w == WPS - 1 && m == 31) {
        #pragma unroll
        for (int i = 0; i < 8; ++i)
            out[B_N * T_LEN + b*16 + 8*kh + i] = Hd[i] - 1.f;
    }
}

extern "C" void kernel_launch(void* const* d_in, const int* in_sizes, int n_in,
                              void* d_out, int out_size, void* d_ws, size_t ws_size,
                              hipStream_t stream) {
    (void)in_sizes; (void)n_in; (void)d_ws; (void)ws_size; (void)out_size;
    hipLaunchKernelGGL(hyper_gru_kernel, dim3(B_N * WPS), dim3(64), 0, stream,
        (const float*)d_in[0],  (const float*)d_in[1],  (const float*)d_in[2],
        (const float*)d_in[3],  (const float*)d_in[4],  (const float*)d_in[5],  (const float*)d_in[6],
        (const float*)d_in[7],  (const float*)d_in[8],  (const float*)d_in[9],  (const float*)d_in[10],
        (const float*)d_in[11], (const float*)d_in[12], (const float*)d_in[13], (const float*)d_in[14],
        (const float*)d_in[15], (const float*)d_in[16],
        (float*)d_out);
}